// Round 2
// baseline (402.136 us; speedup 1.0000x reference)
//
#include <hip/hip_runtime.h>
#include <cstdint>
#include <cstddef>

#define IN_DIM 128
#define OUT_DIM 128

// ------------------------------------------------------------------ utils
__global__ void k_zero_i32(int* __restrict__ p, int n) {
  int i = blockIdx.x * blockDim.x + threadIdx.x;
  int st = gridDim.x * blockDim.x;
  for (; i < n; i += st) p[i] = 0;
}

__global__ void k_zero_f32(float* __restrict__ p, long long n) {
  long long i = (long long)blockIdx.x * blockDim.x + threadIdx.x;
  long long st = (long long)gridDim.x * blockDim.x;
  for (; i < n; i += st) p[i] = 0.0f;
}

// ------------------------------------------------------------------ degree histogram (dst, self-loop added later as +1)
__global__ void k_hist(const int* __restrict__ dst, int E, int* __restrict__ deg) {
  int i = blockIdx.x * blockDim.x + threadIdx.x;
  int st = gridDim.x * blockDim.x;
  for (; i < E; i += st) {
    atomicAdd(&deg[dst[i]], 1);
  }
}

__global__ void k_dinv(const int* __restrict__ deg, float* __restrict__ dinv, int n) {
  int i = blockIdx.x * blockDim.x + threadIdx.x;
  int st = gridDim.x * blockDim.x;
  for (; i < n; i += st) {
    dinv[i] = rsqrtf((float)(deg[i] + 1));  // +1 = self-loop; always > 0
  }
}

// ------------------------------------------------------------------ scan (exclusive prefix sum of deg -> row_start)
__global__ __launch_bounds__(1024) void k_scan_partial(const int* __restrict__ deg, int* __restrict__ bsum, int n) {
  __shared__ int lds[1024];
  int i = blockIdx.x * 1024 + threadIdx.x;
  int v = (i < n) ? deg[i] : 0;
  lds[threadIdx.x] = v;
  __syncthreads();
  for (int off = 512; off > 0; off >>= 1) {
    if (threadIdx.x < off) lds[threadIdx.x] += lds[threadIdx.x + off];
    __syncthreads();
  }
  if (threadIdx.x == 0) bsum[blockIdx.x] = lds[0];
}

__global__ void k_scan_bsum(const int* __restrict__ bsum, int* __restrict__ boff, int nB) {
  if (blockIdx.x == 0 && threadIdx.x == 0) {
    int run = 0;
    for (int i = 0; i < nB; ++i) { boff[i] = run; run += bsum[i]; }
  }
}

__global__ __launch_bounds__(1024) void k_scan_final(const int* __restrict__ deg, const int* __restrict__ boff,
                                                     int* __restrict__ row_start, int* __restrict__ cursor, int n) {
  __shared__ int lds[1024];
  int i = blockIdx.x * 1024 + threadIdx.x;
  int v = (i < n) ? deg[i] : 0;
  lds[threadIdx.x] = v;
  __syncthreads();
  for (int off = 1; off < 1024; off <<= 1) {
    int t = (threadIdx.x >= off) ? lds[threadIdx.x - off] : 0;
    __syncthreads();
    lds[threadIdx.x] += t;
    __syncthreads();
  }
  if (i < n) {
    int excl = boff[blockIdx.x] + lds[threadIdx.x] - v;
    row_start[i] = excl;
    cursor[i] = excl;
    if (i == n - 1) row_start[n] = excl + v;  // total = E
  }
}

// ------------------------------------------------------------------ CSR fill (order within a row nondeterministic; fp32 sum reorder << threshold)
__global__ void k_fill(const int* __restrict__ ei, int E, int* __restrict__ cursor, int* __restrict__ csr_src) {
  int i = blockIdx.x * blockDim.x + threadIdx.x;
  int st = gridDim.x * blockDim.x;
  for (; i < E; i += st) {
    int s = ei[i];
    int d = ei[E + i];
    int pos = atomicAdd(&cursor[d], 1);
    csr_src[pos] = s;
  }
}

// ------------------------------------------------------------------ GEMM: g[r][c] = (x[r] @ W[:,c]) * dinv[r]
// fp32 vector path (no fp32 MFMA on CDNA4). BM=128, BN=128(all), BK=32, 8x8/thread.
__global__ __launch_bounds__(256) void k_gemm_scale(const float* __restrict__ x, const float* __restrict__ W,
                                                    const float* __restrict__ dinv, float* __restrict__ g, int M) {
  __shared__ float xT[32][128];  // [k][row]  16 KB
  __shared__ float Ws[32][128];  // [k][col]  16 KB
  const int tid = threadIdx.x;
  const int tc = tid & 15;   // col group: cols tc*8 .. tc*8+7
  const int tr = tid >> 4;   // row group: rows tr*8 .. tr*8+7
  const int row0 = blockIdx.x * 128;
  const int lr = tid & 127;          // staging row
  const int lk = (tid >> 7) * 16;    // staging k offset (0 or 16)

  float acc[8][8] = {};

  for (int k0 = 0; k0 < IN_DIM; k0 += 32) {
    int grow = row0 + lr;
    if (grow >= M) grow = M - 1;  // clamp (stores are guarded)
    const float4* xp = (const float4*)(x + (size_t)grow * IN_DIM + k0 + lk);
    float4 a0 = xp[0], a1 = xp[1], a2 = xp[2], a3 = xp[3];
    const float4* wp = (const float4*)(W + (size_t)(k0 + (tid >> 3)) * OUT_DIM + (tid & 7) * 16);
    float4 w0 = wp[0], w1 = wp[1], w2 = wp[2], w3 = wp[3];

    __syncthreads();  // previous tile fully consumed
    xT[lk + 0][lr] = a0.x;  xT[lk + 1][lr] = a0.y;  xT[lk + 2][lr] = a0.z;  xT[lk + 3][lr] = a0.w;
    xT[lk + 4][lr] = a1.x;  xT[lk + 5][lr] = a1.y;  xT[lk + 6][lr] = a1.z;  xT[lk + 7][lr] = a1.w;
    xT[lk + 8][lr] = a2.x;  xT[lk + 9][lr] = a2.y;  xT[lk + 10][lr] = a2.z; xT[lk + 11][lr] = a2.w;
    xT[lk + 12][lr] = a3.x; xT[lk + 13][lr] = a3.y; xT[lk + 14][lr] = a3.z; xT[lk + 15][lr] = a3.w;
    float4* wsp = (float4*)&Ws[tid >> 3][(tid & 7) * 16];
    wsp[0] = w0; wsp[1] = w1; wsp[2] = w2; wsp[3] = w3;
    __syncthreads();

#pragma unroll
    for (int k = 0; k < 32; ++k) {
      float xv[8], wv[8];
      *(float4*)&xv[0] = *(const float4*)&xT[k][tr * 8];
      *(float4*)&xv[4] = *(const float4*)&xT[k][tr * 8 + 4];
      *(float4*)&wv[0] = *(const float4*)&Ws[k][tc * 8];
      *(float4*)&wv[4] = *(const float4*)&Ws[k][tc * 8 + 4];
#pragma unroll
      for (int ii = 0; ii < 8; ++ii)
#pragma unroll
        for (int jj = 0; jj < 8; ++jj)
          acc[ii][jj] = fmaf(xv[ii], wv[jj], acc[ii][jj]);
    }
  }

#pragma unroll
  for (int ii = 0; ii < 8; ++ii) {
    int r = row0 + tr * 8 + ii;
    if (r < M) {
      float s = dinv[r];
      float4 o0 = make_float4(acc[ii][0] * s, acc[ii][1] * s, acc[ii][2] * s, acc[ii][3] * s);
      float4 o1 = make_float4(acc[ii][4] * s, acc[ii][5] * s, acc[ii][6] * s, acc[ii][7] * s);
      float4* gp = (float4*)(g + (size_t)r * OUT_DIM + tc * 8);
      gp[0] = o0;
      gp[1] = o1;
    }
  }
}

// ------------------------------------------------------------------ pull aggregation: one wave per node, lane owns 2 cols
__global__ __launch_bounds__(256) void k_agg(const float* __restrict__ g, const int* __restrict__ row_start,
                                             const int* __restrict__ csr_src, const float* __restrict__ dinv,
                                             const float* __restrict__ bias, float* __restrict__ out, int n) {
  const int lane = threadIdx.x & 63;
  const int wave = __builtin_amdgcn_readfirstlane(threadIdx.x >> 6);
  const int wpb = blockDim.x >> 6;
  const int nWaves = gridDim.x * wpb;
  const int c2 = lane * 2;
  const float2 bb = *(const float2*)(bias + c2);

  for (int node = blockIdx.x * wpb + wave; node < n; node += nWaves) {
    const int s = row_start[node];
    const int e = row_start[node + 1];
    float2 acc = *(const float2*)(g + (size_t)node * OUT_DIM + c2);  // self-loop term
    int i = s;
    for (; i + 4 <= e; i += 4) {
      int s0 = csr_src[i + 0];
      int s1 = csr_src[i + 1];
      int s2 = csr_src[i + 2];
      int s3 = csr_src[i + 3];
      float2 v0 = *(const float2*)(g + (size_t)s0 * OUT_DIM + c2);
      float2 v1 = *(const float2*)(g + (size_t)s1 * OUT_DIM + c2);
      float2 v2 = *(const float2*)(g + (size_t)s2 * OUT_DIM + c2);
      float2 v3 = *(const float2*)(g + (size_t)s3 * OUT_DIM + c2);
      acc.x += (v0.x + v1.x) + (v2.x + v3.x);
      acc.y += (v0.y + v1.y) + (v2.y + v3.y);
    }
    for (; i < e; ++i) {
      int s0 = csr_src[i];
      float2 v = *(const float2*)(g + (size_t)s0 * OUT_DIM + c2);
      acc.x += v.x;
      acc.y += v.y;
    }
    const float di = dinv[node];
    float2 o;
    o.x = fmaxf(fmaf(acc.x, di, bb.x), 0.0f);
    o.y = fmaxf(fmaf(acc.y, di, bb.y), 0.0f);
    *(float2*)(out + (size_t)node * OUT_DIM + c2) = o;
  }
}

// ------------------------------------------------------------------ fallback (small ws): atomic scatter
__global__ __launch_bounds__(256) void k_scatter(const int* __restrict__ ei, int E,
                                                 const float* __restrict__ g, float* __restrict__ out) {
  const int lane = threadIdx.x & 63;
  const int wave = __builtin_amdgcn_readfirstlane(threadIdx.x >> 6);
  const int wpb = blockDim.x >> 6;
  const int nWaves = gridDim.x * wpb;
  const int c2 = lane * 2;
  for (int e = blockIdx.x * wpb + wave; e < E; e += nWaves) {
    int s = ei[e];
    int d = ei[E + e];
    float2 v = *(const float2*)(g + (size_t)s * OUT_DIM + c2);
    atomicAdd(&out[(size_t)d * OUT_DIM + c2 + 0], v.x);
    atomicAdd(&out[(size_t)d * OUT_DIM + c2 + 1], v.y);
  }
}

__global__ void k_finalize(const float* __restrict__ g, const float* __restrict__ dinv,
                           const float* __restrict__ bias, float* __restrict__ out, int n) {
  int i = blockIdx.x * blockDim.x + threadIdx.x;
  int st = gridDim.x * blockDim.x;
  int total = n * OUT_DIM;
  for (; i < total; i += st) {
    int node = i >> 7;
    float v = (out[i] + g[i]) * dinv[node] + bias[i & 127];
    out[i] = fmaxf(v, 0.0f);
  }
}

// ------------------------------------------------------------------ launch
extern "C" void kernel_launch(void* const* d_in, const int* in_sizes, int n_in,
                              void* d_out, int out_size, void* d_ws, size_t ws_size,
                              hipStream_t stream) {
  const float* x = (const float*)d_in[0];
  const int* ei = (const int*)d_in[1];   // int64 in reference -> delivered as int32
  const float* W = (const float*)d_in[2];
  const float* bias = (const float*)d_in[3];
  float* out = (float*)d_out;

  const int N = in_sizes[0] / IN_DIM;  // 100000
  const int E = in_sizes[1] / 2;       // 1600000

  char* ws = (char*)d_ws;
  size_t off = 0;
  auto alloc = [&](size_t bytes) -> void* {
    void* p = ws + off;
    off += (bytes + 255) & ~(size_t)255;
    return p;
  };
  float* g = (float*)alloc((size_t)N * OUT_DIM * sizeof(float));  // 51.2 MB
  int* deg = (int*)alloc((size_t)N * sizeof(int));
  float* dinv = (float*)alloc((size_t)N * sizeof(float));
  int* row_start = (int*)alloc((size_t)(N + 1) * sizeof(int));
  int* cursor = (int*)alloc((size_t)N * sizeof(int));
  int* bsum = (int*)alloc(1024 * sizeof(int));
  int* boff = (int*)alloc(1024 * sizeof(int));
  size_t base_need = off;
  int* csr = (int*)alloc((size_t)E * sizeof(int));  // 6.4 MB
  size_t full_need = off;

  if (ws_size < base_need) return;  // cannot run at all
  const bool full = (ws_size >= full_need);

  // degree + dinv
  k_zero_i32<<<256, 256, 0, stream>>>(deg, N);
  k_hist<<<2048, 256, 0, stream>>>(ei + E, E, deg);
  k_dinv<<<512, 256, 0, stream>>>(deg, dinv, N);

  // g = (x @ W) * dinv[row]
  int mBlocks = (N + 127) / 128;
  k_gemm_scale<<<mBlocks, 256, 0, stream>>>(x, W, dinv, g, N);

  if (full) {
    int nB = (N + 1023) / 1024;
    k_scan_partial<<<nB, 1024, 0, stream>>>(deg, bsum, N);
    k_scan_bsum<<<1, 64, 0, stream>>>(bsum, boff, nB);
    k_scan_final<<<nB, 1024, 0, stream>>>(deg, boff, row_start, cursor, N);
    k_fill<<<2048, 256, 0, stream>>>(ei, E, cursor, csr);
    k_agg<<<2048, 256, 0, stream>>>(g, row_start, csr, dinv, bias, out, N);
  } else {
    k_zero_f32<<<2048, 256, 0, stream>>>(out, (long long)N * OUT_DIM);
    k_scatter<<<4096, 256, 0, stream>>>(ei, E, g, out);
    k_finalize<<<2048, 256, 0, stream>>>(g, dinv, bias, out, N);
  }
}

// Round 3
// 337.736 us; speedup vs baseline: 1.1907x; 1.1907x over previous
//
#include <hip/hip_runtime.h>
#include <cstdint>
#include <cstddef>

#define IN_DIM 128
#define OUT_DIM 128

// ------------------------------------------------------------------ utils
__global__ void k_zero_i32(int* __restrict__ p, int n) {
  int i = blockIdx.x * blockDim.x + threadIdx.x;
  int st = gridDim.x * blockDim.x;
  for (; i < n; i += st) p[i] = 0;
}

__global__ void k_zero_f32(float* __restrict__ p, long long n) {
  long long i = (long long)blockIdx.x * blockDim.x + threadIdx.x;
  long long st = (long long)gridDim.x * blockDim.x;
  for (; i < n; i += st) p[i] = 0.0f;
}

// ------------------------------------------------------------------ degree histogram (dst, self-loop added later as +1)
__global__ void k_hist(const int* __restrict__ dst, int E, int* __restrict__ deg) {
  int i = blockIdx.x * blockDim.x + threadIdx.x;
  int st = gridDim.x * blockDim.x;
  for (; i < E; i += st) {
    atomicAdd(&deg[dst[i]], 1);
  }
}

__global__ void k_dinv(const int* __restrict__ deg, float* __restrict__ dinv, int n) {
  int i = blockIdx.x * blockDim.x + threadIdx.x;
  int st = gridDim.x * blockDim.x;
  for (; i < n; i += st) {
    dinv[i] = rsqrtf((float)(deg[i] + 1));  // +1 = self-loop; always > 0
  }
}

// ------------------------------------------------------------------ scan (exclusive prefix sum of deg -> row_start)
__global__ __launch_bounds__(1024) void k_scan_partial(const int* __restrict__ deg, int* __restrict__ bsum, int n) {
  __shared__ int lds[1024];
  int i = blockIdx.x * 1024 + threadIdx.x;
  int v = (i < n) ? deg[i] : 0;
  lds[threadIdx.x] = v;
  __syncthreads();
  for (int off = 512; off > 0; off >>= 1) {
    if (threadIdx.x < off) lds[threadIdx.x] += lds[threadIdx.x + off];
    __syncthreads();
  }
  if (threadIdx.x == 0) bsum[blockIdx.x] = lds[0];
}

__global__ void k_scan_bsum(const int* __restrict__ bsum, int* __restrict__ boff, int nB) {
  if (blockIdx.x == 0 && threadIdx.x == 0) {
    int run = 0;
    for (int i = 0; i < nB; ++i) { boff[i] = run; run += bsum[i]; }
  }
}

__global__ __launch_bounds__(1024) void k_scan_final(const int* __restrict__ deg, const int* __restrict__ boff,
                                                     int* __restrict__ row_start, int* __restrict__ cursor, int n) {
  __shared__ int lds[1024];
  int i = blockIdx.x * 1024 + threadIdx.x;
  int v = (i < n) ? deg[i] : 0;
  lds[threadIdx.x] = v;
  __syncthreads();
  for (int off = 1; off < 1024; off <<= 1) {
    int t = (threadIdx.x >= off) ? lds[threadIdx.x - off] : 0;
    __syncthreads();
    lds[threadIdx.x] += t;
    __syncthreads();
  }
  if (i < n) {
    int excl = boff[blockIdx.x] + lds[threadIdx.x] - v;
    row_start[i] = excl;
    cursor[i] = excl;
    if (i == n - 1) row_start[n] = excl + v;  // total = E
  }
}

// ------------------------------------------------------------------ CSR fill, XCD-range-partitioned.
// dst-space split into 8 contiguous ranges; range r handled only by blocks with
// blockIdx&7==r (which land on XCD r under the round-robin mapping — perf
// heuristic only). All csr/cursor lines for a range are then owned by ONE XCD's
// L2: the 16 dword writes per 64B line coalesce before a single eviction,
// killing the 16x write amplification measured in round 2 (106 MB -> ~7 MB).
// Cost: each of the 8 range-groups streams all edges (8x read, L3-resident).
__global__ __launch_bounds__(256) void k_fill_part(const int* __restrict__ ei, int E,
                                                   int* __restrict__ cursor, int* __restrict__ csr_src,
                                                   int n) {
  const int r = blockIdx.x & 7;
  const int gblk = blockIdx.x >> 3;
  const int nblk = gridDim.x >> 3;
  const int rs = (n + 7) >> 3;  // range size
  const int lo = r * rs;
  const int hi = (lo + rs < n) ? lo + rs : n;

  int i = gblk * blockDim.x + threadIdx.x;
  const int st = nblk * blockDim.x;
  for (; i < E; i += st) {
    int d = ei[E + i];
    if (d >= lo && d < hi) {
      int s = ei[i];
      int pos = atomicAdd(&cursor[d], 1);
      csr_src[pos] = s;
    }
  }
}

// ------------------------------------------------------------------ GEMM: g[r][c] = (x[r] @ W[:,c]) * dinv[r]
// fp32 vector path (no fp32 MFMA on CDNA4). BM=128, BN=128(all), BK=32, 8x8/thread.
__global__ __launch_bounds__(256) void k_gemm_scale(const float* __restrict__ x, const float* __restrict__ W,
                                                    const float* __restrict__ dinv, float* __restrict__ g, int M) {
  __shared__ float xT[32][128];  // [k][row]  16 KB
  __shared__ float Ws[32][128];  // [k][col]  16 KB
  const int tid = threadIdx.x;
  const int tc = tid & 15;   // col group: cols tc*8 .. tc*8+7
  const int tr = tid >> 4;   // row group: rows tr*8 .. tr*8+7
  const int row0 = blockIdx.x * 128;
  const int lr = tid & 127;          // staging row
  const int lk = (tid >> 7) * 16;    // staging k offset (0 or 16)

  float acc[8][8] = {};

  for (int k0 = 0; k0 < IN_DIM; k0 += 32) {
    int grow = row0 + lr;
    if (grow >= M) grow = M - 1;  // clamp (stores are guarded)
    const float4* xp = (const float4*)(x + (size_t)grow * IN_DIM + k0 + lk);
    float4 a0 = xp[0], a1 = xp[1], a2 = xp[2], a3 = xp[3];
    const float4* wp = (const float4*)(W + (size_t)(k0 + (tid >> 3)) * OUT_DIM + (tid & 7) * 16);
    float4 w0 = wp[0], w1 = wp[1], w2 = wp[2], w3 = wp[3];

    __syncthreads();  // previous tile fully consumed
    xT[lk + 0][lr] = a0.x;  xT[lk + 1][lr] = a0.y;  xT[lk + 2][lr] = a0.z;  xT[lk + 3][lr] = a0.w;
    xT[lk + 4][lr] = a1.x;  xT[lk + 5][lr] = a1.y;  xT[lk + 6][lr] = a1.z;  xT[lk + 7][lr] = a1.w;
    xT[lk + 8][lr] = a2.x;  xT[lk + 9][lr] = a2.y;  xT[lk + 10][lr] = a2.z; xT[lk + 11][lr] = a2.w;
    xT[lk + 12][lr] = a3.x; xT[lk + 13][lr] = a3.y; xT[lk + 14][lr] = a3.z; xT[lk + 15][lr] = a3.w;
    float4* wsp = (float4*)&Ws[tid >> 3][(tid & 7) * 16];
    wsp[0] = w0; wsp[1] = w1; wsp[2] = w2; wsp[3] = w3;
    __syncthreads();

#pragma unroll
    for (int k = 0; k < 32; ++k) {
      float xv[8], wv[8];
      *(float4*)&xv[0] = *(const float4*)&xT[k][tr * 8];
      *(float4*)&xv[4] = *(const float4*)&xT[k][tr * 8 + 4];
      *(float4*)&wv[0] = *(const float4*)&Ws[k][tc * 8];
      *(float4*)&wv[4] = *(const float4*)&Ws[k][tc * 8 + 4];
#pragma unroll
      for (int ii = 0; ii < 8; ++ii)
#pragma unroll
        for (int jj = 0; jj < 8; ++jj)
          acc[ii][jj] = fmaf(xv[ii], wv[jj], acc[ii][jj]);
    }
  }

#pragma unroll
  for (int ii = 0; ii < 8; ++ii) {
    int r = row0 + tr * 8 + ii;
    if (r < M) {
      float s = dinv[r];
      float4 o0 = make_float4(acc[ii][0] * s, acc[ii][1] * s, acc[ii][2] * s, acc[ii][3] * s);
      float4 o1 = make_float4(acc[ii][4] * s, acc[ii][5] * s, acc[ii][6] * s, acc[ii][7] * s);
      float4* gp = (float4*)(g + (size_t)r * OUT_DIM + tc * 8);
      gp[0] = o0;
      gp[1] = o1;
    }
  }
}

// ------------------------------------------------------------------ pull aggregation: one wave per node, lane owns 2 cols
__global__ __launch_bounds__(256) void k_agg(const float* __restrict__ g, const int* __restrict__ row_start,
                                             const int* __restrict__ csr_src, const float* __restrict__ dinv,
                                             const float* __restrict__ bias, float* __restrict__ out, int n) {
  const int lane = threadIdx.x & 63;
  const int wave = __builtin_amdgcn_readfirstlane(threadIdx.x >> 6);
  const int wpb = blockDim.x >> 6;
  const int nWaves = gridDim.x * wpb;
  const int c2 = lane * 2;
  const float2 bb = *(const float2*)(bias + c2);

  for (int node = blockIdx.x * wpb + wave; node < n; node += nWaves) {
    const int s = row_start[node];
    const int e = row_start[node + 1];
    float2 acc = *(const float2*)(g + (size_t)node * OUT_DIM + c2);  // self-loop term
    int i = s;
    for (; i + 4 <= e; i += 4) {
      int s0 = csr_src[i + 0];
      int s1 = csr_src[i + 1];
      int s2 = csr_src[i + 2];
      int s3 = csr_src[i + 3];
      float2 v0 = *(const float2*)(g + (size_t)s0 * OUT_DIM + c2);
      float2 v1 = *(const float2*)(g + (size_t)s1 * OUT_DIM + c2);
      float2 v2 = *(const float2*)(g + (size_t)s2 * OUT_DIM + c2);
      float2 v3 = *(const float2*)(g + (size_t)s3 * OUT_DIM + c2);
      acc.x += (v0.x + v1.x) + (v2.x + v3.x);
      acc.y += (v0.y + v1.y) + (v2.y + v3.y);
    }
    for (; i < e; ++i) {
      int s0 = csr_src[i];
      float2 v = *(const float2*)(g + (size_t)s0 * OUT_DIM + c2);
      acc.x += v.x;
      acc.y += v.y;
    }
    const float di = dinv[node];
    float2 o;
    o.x = fmaxf(fmaf(acc.x, di, bb.x), 0.0f);
    o.y = fmaxf(fmaf(acc.y, di, bb.y), 0.0f);
    *(float2*)(out + (size_t)node * OUT_DIM + c2) = o;
  }
}

// ------------------------------------------------------------------ fallback (small ws): atomic scatter
__global__ __launch_bounds__(256) void k_scatter(const int* __restrict__ ei, int E,
                                                 const float* __restrict__ g, float* __restrict__ out) {
  const int lane = threadIdx.x & 63;
  const int wave = __builtin_amdgcn_readfirstlane(threadIdx.x >> 6);
  const int wpb = blockDim.x >> 6;
  const int nWaves = gridDim.x * wpb;
  const int c2 = lane * 2;
  for (int e = blockIdx.x * wpb + wave; e < E; e += nWaves) {
    int s = ei[e];
    int d = ei[E + e];
    float2 v = *(const float2*)(g + (size_t)s * OUT_DIM + c2);
    atomicAdd(&out[(size_t)d * OUT_DIM + c2 + 0], v.x);
    atomicAdd(&out[(size_t)d * OUT_DIM + c2 + 1], v.y);
  }
}

__global__ void k_finalize(const float* __restrict__ g, const float* __restrict__ dinv,
                           const float* __restrict__ bias, float* __restrict__ out, int n) {
  int i = blockIdx.x * blockDim.x + threadIdx.x;
  int st = gridDim.x * blockDim.x;
  int total = n * OUT_DIM;
  for (; i < total; i += st) {
    int node = i >> 7;
    float v = (out[i] + g[i]) * dinv[node] + bias[i & 127];
    out[i] = fmaxf(v, 0.0f);
  }
}

// ------------------------------------------------------------------ launch
extern "C" void kernel_launch(void* const* d_in, const int* in_sizes, int n_in,
                              void* d_out, int out_size, void* d_ws, size_t ws_size,
                              hipStream_t stream) {
  const float* x = (const float*)d_in[0];
  const int* ei = (const int*)d_in[1];   // int64 in reference -> delivered as int32
  const float* W = (const float*)d_in[2];
  const float* bias = (const float*)d_in[3];
  float* out = (float*)d_out;

  const int N = in_sizes[0] / IN_DIM;  // 100000
  const int E = in_sizes[1] / 2;       // 1600000

  char* ws = (char*)d_ws;
  size_t off = 0;
  auto alloc = [&](size_t bytes) -> void* {
    void* p = ws + off;
    off += (bytes + 255) & ~(size_t)255;
    return p;
  };
  float* g = (float*)alloc((size_t)N * OUT_DIM * sizeof(float));  // 51.2 MB
  int* deg = (int*)alloc((size_t)N * sizeof(int));
  float* dinv = (float*)alloc((size_t)N * sizeof(float));
  int* row_start = (int*)alloc((size_t)(N + 1) * sizeof(int));
  int* cursor = (int*)alloc((size_t)N * sizeof(int));
  int* bsum = (int*)alloc(1024 * sizeof(int));
  int* boff = (int*)alloc(1024 * sizeof(int));
  size_t base_need = off;
  int* csr = (int*)alloc((size_t)E * sizeof(int));  // 6.4 MB
  size_t full_need = off;

  if (ws_size < base_need) return;  // cannot run at all
  const bool full = (ws_size >= full_need);

  // degree + dinv
  k_zero_i32<<<256, 256, 0, stream>>>(deg, N);
  k_hist<<<2048, 256, 0, stream>>>(ei + E, E, deg);
  k_dinv<<<512, 256, 0, stream>>>(deg, dinv, N);

  // g = (x @ W) * dinv[row]
  int mBlocks = (N + 127) / 128;
  k_gemm_scale<<<mBlocks, 256, 0, stream>>>(x, W, dinv, g, N);

  if (full) {
    int nB = (N + 1023) / 1024;
    k_scan_partial<<<nB, 1024, 0, stream>>>(deg, bsum, N);
    k_scan_bsum<<<1, 64, 0, stream>>>(bsum, boff, nB);
    k_scan_final<<<nB, 1024, 0, stream>>>(deg, boff, row_start, cursor, N);
    k_fill_part<<<2048, 256, 0, stream>>>(ei, E, cursor, csr, N);
    k_agg<<<2048, 256, 0, stream>>>(g, row_start, csr, dinv, bias, out, N);
  } else {
    k_zero_f32<<<2048, 256, 0, stream>>>(out, (long long)N * OUT_DIM);
    k_scatter<<<4096, 256, 0, stream>>>(ei, E, g, out);
    k_finalize<<<2048, 256, 0, stream>>>(g, dinv, bias, out, N);
  }
}

// Round 4
// 283.378 us; speedup vs baseline: 1.4191x; 1.1918x over previous
//
#include <hip/hip_runtime.h>
#include <cstdint>
#include <cstddef>

#define IN_DIM 128
#define OUT_DIM 128

// bf16 helpers (OCP bf16 = top 16 bits of fp32, RNE)
__device__ __forceinline__ unsigned short f2bf(float f) {
  unsigned int u = __float_as_uint(f);
  u = (u + 0x7FFFu + ((u >> 16) & 1u)) >> 16;
  return (unsigned short)u;
}
__device__ __forceinline__ float bf_lo(unsigned int v) { return __uint_as_float(v << 16); }
__device__ __forceinline__ float bf_hi(unsigned int v) { return __uint_as_float(v & 0xFFFF0000u); }

// ------------------------------------------------------------------ utils
__global__ void k_zero_i32(int* __restrict__ p, int n) {
  int i = blockIdx.x * blockDim.x + threadIdx.x;
  int st = gridDim.x * blockDim.x;
  for (; i < n; i += st) p[i] = 0;
}

__global__ void k_zero_f32(float* __restrict__ p, long long n) {
  long long i = (long long)blockIdx.x * blockDim.x + threadIdx.x;
  long long st = (long long)gridDim.x * blockDim.x;
  for (; i < n; i += st) p[i] = 0.0f;
}

// ------------------------------------------------------------------ degree histogram (dst, self-loop added later as +1)
__global__ void k_hist(const int* __restrict__ dst, int E, int* __restrict__ deg) {
  int i = blockIdx.x * blockDim.x + threadIdx.x;
  int st = gridDim.x * blockDim.x;
  for (; i < E; i += st) {
    atomicAdd(&deg[dst[i]], 1);
  }
}

__global__ void k_dinv(const int* __restrict__ deg, float* __restrict__ dinv, int n) {
  int i = blockIdx.x * blockDim.x + threadIdx.x;
  int st = gridDim.x * blockDim.x;
  for (; i < n; i += st) {
    dinv[i] = rsqrtf((float)(deg[i] + 1));  // +1 = self-loop; always > 0
  }
}

// ------------------------------------------------------------------ scan (exclusive prefix sum of deg -> row_start)
__global__ __launch_bounds__(1024) void k_scan_partial(const int* __restrict__ deg, int* __restrict__ bsum, int n) {
  __shared__ int lds[1024];
  int i = blockIdx.x * 1024 + threadIdx.x;
  int v = (i < n) ? deg[i] : 0;
  lds[threadIdx.x] = v;
  __syncthreads();
  for (int off = 512; off > 0; off >>= 1) {
    if (threadIdx.x < off) lds[threadIdx.x] += lds[threadIdx.x + off];
    __syncthreads();
  }
  if (threadIdx.x == 0) bsum[blockIdx.x] = lds[0];
}

__global__ void k_scan_bsum(const int* __restrict__ bsum, int* __restrict__ boff, int nB) {
  if (blockIdx.x == 0 && threadIdx.x == 0) {
    int run = 0;
    for (int i = 0; i < nB; ++i) { boff[i] = run; run += bsum[i]; }
  }
}

__global__ __launch_bounds__(1024) void k_scan_final(const int* __restrict__ deg, const int* __restrict__ boff,
                                                     int* __restrict__ row_start, int* __restrict__ cursor, int n) {
  __shared__ int lds[1024];
  int i = blockIdx.x * 1024 + threadIdx.x;
  int v = (i < n) ? deg[i] : 0;
  lds[threadIdx.x] = v;
  __syncthreads();
  for (int off = 1; off < 1024; off <<= 1) {
    int t = (threadIdx.x >= off) ? lds[threadIdx.x - off] : 0;
    __syncthreads();
    lds[threadIdx.x] += t;
    __syncthreads();
  }
  if (i < n) {
    int excl = boff[blockIdx.x] + lds[threadIdx.x] - v;
    row_start[i] = excl;
    cursor[i] = excl;
    if (i == n - 1) row_start[n] = excl + v;  // total = E
  }
}

// ------------------------------------------------------------------ CSR fill, XCD-range-partitioned (round-3 win: 144us -> ~79us).
// Unroll x4 with upfront dst loads for MLP this round.
__global__ __launch_bounds__(256) void k_fill_part(const int* __restrict__ ei, int E,
                                                   int* __restrict__ cursor, int* __restrict__ csr_src,
                                                   int n) {
  const int r = blockIdx.x & 7;
  const int gblk = blockIdx.x >> 3;
  const int nblk = gridDim.x >> 3;
  const int rs = (n + 7) >> 3;  // range size
  const int lo = r * rs;
  const int hi = (lo + rs < n) ? lo + rs : n;

  const int st = nblk * blockDim.x;
  int i = gblk * blockDim.x + threadIdx.x;
  const int* dstp = ei + E;

  for (; i + 3 * st < E; i += 4 * st) {
    int d0 = dstp[i];
    int d1 = dstp[i + st];
    int d2 = dstp[i + 2 * st];
    int d3 = dstp[i + 3 * st];
    if (d0 >= lo && d0 < hi) { int pos = atomicAdd(&cursor[d0], 1); csr_src[pos] = ei[i]; }
    if (d1 >= lo && d1 < hi) { int pos = atomicAdd(&cursor[d1], 1); csr_src[pos] = ei[i + st]; }
    if (d2 >= lo && d2 < hi) { int pos = atomicAdd(&cursor[d2], 1); csr_src[pos] = ei[i + 2 * st]; }
    if (d3 >= lo && d3 < hi) { int pos = atomicAdd(&cursor[d3], 1); csr_src[pos] = ei[i + 3 * st]; }
  }
  for (; i < E; i += st) {
    int d = dstp[i];
    if (d >= lo && d < hi) { int pos = atomicAdd(&cursor[d], 1); csr_src[pos] = ei[i]; }
  }
}

// ------------------------------------------------------------------ GEMM: gb[r][c] = bf16((x[r] @ W[:,c]) * dinv[r])
// fp32 vector path (no fp32 MFMA on CDNA4). BM=128, BN=128(all), BK=32, 8x8/thread.
__global__ __launch_bounds__(256) void k_gemm_scale(const float* __restrict__ x, const float* __restrict__ W,
                                                    const float* __restrict__ dinv,
                                                    unsigned short* __restrict__ gb, int M) {
  __shared__ float xT[32][128];  // [k][row]  16 KB
  __shared__ float Ws[32][128];  // [k][col]  16 KB
  const int tid = threadIdx.x;
  const int tc = tid & 15;   // col group: cols tc*8 .. tc*8+7
  const int tr = tid >> 4;   // row group: rows tr*8 .. tr*8+7
  const int row0 = blockIdx.x * 128;
  const int lr = tid & 127;          // staging row
  const int lk = (tid >> 7) * 16;    // staging k offset (0 or 16)

  float acc[8][8] = {};

  for (int k0 = 0; k0 < IN_DIM; k0 += 32) {
    int grow = row0 + lr;
    if (grow >= M) grow = M - 1;  // clamp (stores are guarded)
    const float4* xp = (const float4*)(x + (size_t)grow * IN_DIM + k0 + lk);
    float4 a0 = xp[0], a1 = xp[1], a2 = xp[2], a3 = xp[3];
    const float4* wp = (const float4*)(W + (size_t)(k0 + (tid >> 3)) * OUT_DIM + (tid & 7) * 16);
    float4 w0 = wp[0], w1 = wp[1], w2 = wp[2], w3 = wp[3];

    __syncthreads();  // previous tile fully consumed
    xT[lk + 0][lr] = a0.x;  xT[lk + 1][lr] = a0.y;  xT[lk + 2][lr] = a0.z;  xT[lk + 3][lr] = a0.w;
    xT[lk + 4][lr] = a1.x;  xT[lk + 5][lr] = a1.y;  xT[lk + 6][lr] = a1.z;  xT[lk + 7][lr] = a1.w;
    xT[lk + 8][lr] = a2.x;  xT[lk + 9][lr] = a2.y;  xT[lk + 10][lr] = a2.z; xT[lk + 11][lr] = a2.w;
    xT[lk + 12][lr] = a3.x; xT[lk + 13][lr] = a3.y; xT[lk + 14][lr] = a3.z; xT[lk + 15][lr] = a3.w;
    float4* wsp = (float4*)&Ws[tid >> 3][(tid & 7) * 16];
    wsp[0] = w0; wsp[1] = w1; wsp[2] = w2; wsp[3] = w3;
    __syncthreads();

#pragma unroll
    for (int k = 0; k < 32; ++k) {
      float xv[8], wv[8];
      *(float4*)&xv[0] = *(const float4*)&xT[k][tr * 8];
      *(float4*)&xv[4] = *(const float4*)&xT[k][tr * 8 + 4];
      *(float4*)&wv[0] = *(const float4*)&Ws[k][tc * 8];
      *(float4*)&wv[4] = *(const float4*)&Ws[k][tc * 8 + 4];
#pragma unroll
      for (int ii = 0; ii < 8; ++ii)
#pragma unroll
        for (int jj = 0; jj < 8; ++jj)
          acc[ii][jj] = fmaf(xv[ii], wv[jj], acc[ii][jj]);
    }
  }

#pragma unroll
  for (int ii = 0; ii < 8; ++ii) {
    int r = row0 + tr * 8 + ii;
    if (r < M) {
      float s = dinv[r];
      uint4 o;
      o.x = (unsigned int)f2bf(acc[ii][0] * s) | ((unsigned int)f2bf(acc[ii][1] * s) << 16);
      o.y = (unsigned int)f2bf(acc[ii][2] * s) | ((unsigned int)f2bf(acc[ii][3] * s) << 16);
      o.z = (unsigned int)f2bf(acc[ii][4] * s) | ((unsigned int)f2bf(acc[ii][5] * s) << 16);
      o.w = (unsigned int)f2bf(acc[ii][6] * s) | ((unsigned int)f2bf(acc[ii][7] * s) << 16);
      *(uint4*)(gb + (size_t)r * OUT_DIM + tc * 8) = o;
    }
  }
}

// ------------------------------------------------------------------ pull aggregation: one wave per node, lane owns 2 cols (bf16 gathers)
__global__ __launch_bounds__(256) void k_agg(const unsigned short* __restrict__ gb, const int* __restrict__ row_start,
                                             const int* __restrict__ csr_src, const float* __restrict__ dinv,
                                             const float* __restrict__ bias, float* __restrict__ out, int n) {
  const int lane = threadIdx.x & 63;
  const int wave = __builtin_amdgcn_readfirstlane(threadIdx.x >> 6);
  const int wpb = blockDim.x >> 6;
  const int nWaves = gridDim.x * wpb;
  const int c2 = lane * 2;
  const float2 bb = *(const float2*)(bias + c2);

  for (int node = blockIdx.x * wpb + wave; node < n; node += nWaves) {
    const int s = row_start[node];
    const int e = row_start[node + 1];
    unsigned int sv = *(const unsigned int*)(gb + (size_t)node * OUT_DIM + c2);  // self-loop term
    float ax = bf_lo(sv), ay = bf_hi(sv);
    int i = s;
    for (; i + 8 <= e; i += 8) {
      // csr indices are wave-uniform -> scalar loads; 8 gathers in flight
      int s0 = csr_src[i + 0], s1 = csr_src[i + 1], s2 = csr_src[i + 2], s3 = csr_src[i + 3];
      int s4 = csr_src[i + 4], s5 = csr_src[i + 5], s6 = csr_src[i + 6], s7 = csr_src[i + 7];
      unsigned int v0 = *(const unsigned int*)(gb + (size_t)s0 * OUT_DIM + c2);
      unsigned int v1 = *(const unsigned int*)(gb + (size_t)s1 * OUT_DIM + c2);
      unsigned int v2 = *(const unsigned int*)(gb + (size_t)s2 * OUT_DIM + c2);
      unsigned int v3 = *(const unsigned int*)(gb + (size_t)s3 * OUT_DIM + c2);
      unsigned int v4 = *(const unsigned int*)(gb + (size_t)s4 * OUT_DIM + c2);
      unsigned int v5 = *(const unsigned int*)(gb + (size_t)s5 * OUT_DIM + c2);
      unsigned int v6 = *(const unsigned int*)(gb + (size_t)s6 * OUT_DIM + c2);
      unsigned int v7 = *(const unsigned int*)(gb + (size_t)s7 * OUT_DIM + c2);
      ax += ((bf_lo(v0) + bf_lo(v1)) + (bf_lo(v2) + bf_lo(v3))) +
            ((bf_lo(v4) + bf_lo(v5)) + (bf_lo(v6) + bf_lo(v7)));
      ay += ((bf_hi(v0) + bf_hi(v1)) + (bf_hi(v2) + bf_hi(v3))) +
            ((bf_hi(v4) + bf_hi(v5)) + (bf_hi(v6) + bf_hi(v7)));
    }
    for (; i < e; ++i) {
      unsigned int v = *(const unsigned int*)(gb + (size_t)csr_src[i] * OUT_DIM + c2);
      ax += bf_lo(v);
      ay += bf_hi(v);
    }
    const float di = dinv[node];
    float2 o;
    o.x = fmaxf(fmaf(ax, di, bb.x), 0.0f);
    o.y = fmaxf(fmaf(ay, di, bb.y), 0.0f);
    *(float2*)(out + (size_t)node * OUT_DIM + c2) = o;
  }
}

// ------------------------------------------------------------------ fallback (small ws): atomic scatter
__global__ __launch_bounds__(256) void k_scatter(const int* __restrict__ ei, int E,
                                                 const unsigned short* __restrict__ gb, float* __restrict__ out) {
  const int lane = threadIdx.x & 63;
  const int wave = __builtin_amdgcn_readfirstlane(threadIdx.x >> 6);
  const int wpb = blockDim.x >> 6;
  const int nWaves = gridDim.x * wpb;
  const int c2 = lane * 2;
  for (int e = blockIdx.x * wpb + wave; e < E; e += nWaves) {
    int s = ei[e];
    int d = ei[E + e];
    unsigned int v = *(const unsigned int*)(gb + (size_t)s * OUT_DIM + c2);
    atomicAdd(&out[(size_t)d * OUT_DIM + c2 + 0], bf_lo(v));
    atomicAdd(&out[(size_t)d * OUT_DIM + c2 + 1], bf_hi(v));
  }
}

__global__ void k_finalize(const unsigned short* __restrict__ gb, const float* __restrict__ dinv,
                           const float* __restrict__ bias, float* __restrict__ out, int n) {
  int i = blockIdx.x * blockDim.x + threadIdx.x;
  int st = gridDim.x * blockDim.x;
  int total = n * OUT_DIM;
  for (; i < total; i += st) {
    int node = i >> 7;
    float gv = __uint_as_float(((unsigned int)gb[i]) << 16);
    float v = (out[i] + gv) * dinv[node] + bias[i & 127];
    out[i] = fmaxf(v, 0.0f);
  }
}

// ------------------------------------------------------------------ launch
extern "C" void kernel_launch(void* const* d_in, const int* in_sizes, int n_in,
                              void* d_out, int out_size, void* d_ws, size_t ws_size,
                              hipStream_t stream) {
  const float* x = (const float*)d_in[0];
  const int* ei = (const int*)d_in[1];   // int64 in reference -> delivered as int32
  const float* W = (const float*)d_in[2];
  const float* bias = (const float*)d_in[3];
  float* out = (float*)d_out;

  const int N = in_sizes[0] / IN_DIM;  // 100000
  const int E = in_sizes[1] / 2;       // 1600000

  char* ws = (char*)d_ws;
  size_t off = 0;
  auto alloc = [&](size_t bytes) -> void* {
    void* p = ws + off;
    off += (bytes + 255) & ~(size_t)255;
    return p;
  };
  unsigned short* gb = (unsigned short*)alloc((size_t)N * OUT_DIM * sizeof(unsigned short));  // 25.6 MB
  int* deg = (int*)alloc((size_t)N * sizeof(int));
  float* dinv = (float*)alloc((size_t)N * sizeof(float));
  int* row_start = (int*)alloc((size_t)(N + 1) * sizeof(int));
  int* cursor = (int*)alloc((size_t)N * sizeof(int));
  int* bsum = (int*)alloc(1024 * sizeof(int));
  int* boff = (int*)alloc(1024 * sizeof(int));
  size_t base_need = off;
  int* csr = (int*)alloc((size_t)E * sizeof(int));  // 6.4 MB
  size_t full_need = off;

  if (ws_size < base_need) return;  // cannot run at all
  const bool full = (ws_size >= full_need);

  // degree + dinv
  k_zero_i32<<<256, 256, 0, stream>>>(deg, N);
  k_hist<<<2048, 256, 0, stream>>>(ei + E, E, deg);
  k_dinv<<<512, 256, 0, stream>>>(deg, dinv, N);

  // gb = bf16((x @ W) * dinv[row])
  int mBlocks = (N + 127) / 128;
  k_gemm_scale<<<mBlocks, 256, 0, stream>>>(x, W, dinv, gb, N);

  if (full) {
    int nB = (N + 1023) / 1024;
    k_scan_partial<<<nB, 1024, 0, stream>>>(deg, bsum, N);
    k_scan_bsum<<<1, 64, 0, stream>>>(bsum, boff, nB);
    k_scan_final<<<nB, 1024, 0, stream>>>(deg, boff, row_start, cursor, N);
    k_fill_part<<<2048, 256, 0, stream>>>(ei, E, cursor, csr, N);
    k_agg<<<2048, 256, 0, stream>>>(gb, row_start, csr, dinv, bias, out, N);
  } else {
    k_zero_f32<<<2048, 256, 0, stream>>>(out, (long long)N * OUT_DIM);
    k_scatter<<<4096, 256, 0, stream>>>(ei, E, gb, out);
    k_finalize<<<2048, 256, 0, stream>>>(gb, dinv, bias, out, N);
  }
}